// Round 13
// baseline (874.089 us; speedup 1.0000x reference)
//
#include <hip/hip_runtime.h>
#include <hip/hip_bf16.h>
#include <math.h>

#define NN 100000
#define NNP 100096          // padded to 1564*64
#define NE 300000
#define HID 128
#define EMB 64
#define NG 4096
#define DEG_CAP 32

typedef __bf16 bf16x8 __attribute__((ext_vector_type(8)));
typedef float  f32x16 __attribute__((ext_vector_type(16)));
typedef short  short8 __attribute__((ext_vector_type(8)));

__device__ __forceinline__ float bf2f(unsigned short u) {
    unsigned int x = ((unsigned int)u) << 16;
    return __builtin_bit_cast(float, x);
}
__device__ __forceinline__ unsigned short f2bf(float f) {
    unsigned int x = __builtin_bit_cast(unsigned int, f);
    unsigned int r = x + 0x7fff + ((x >> 16) & 1);
    return (unsigned short)(r >> 16);
}
__device__ __forceinline__ float sigm(float x) { return 1.f / (1.f + __expf(-x)); }

#define MFMA(A, B, C) __builtin_amdgcn_mfma_f32_32x32x16_bf16( \
    __builtin_bit_cast(bf16x8, A), __builtin_bit_cast(bf16x8, B), C, 0, 0, 0)

// ---------------------------------------------------------------------------
// h init: node_features f32 -> Y0 bf16 [NNP][128]; pad rows zeroed.
// ---------------------------------------------------------------------------
__global__ __launch_bounds__(256) void k_init(const float* __restrict__ nf,
                                              unsigned short* __restrict__ Y) {
    int id = blockIdx.x * 256 + threadIdx.x;   // NNP*HID
    int n = id >> 7, c = id & 127;
    Y[(long)n * HID + c] = (n < NN) ? f2bf(nf[(long)n * HID + c]) : (unsigned short)0;
}

// ---------------------------------------------------------------------------
// CSR build (deg true counts; csr capped at DEG_CAP)
// ---------------------------------------------------------------------------
__global__ __launch_bounds__(256) void k_build_csr(const int* __restrict__ ei,
                                                   int* __restrict__ deg,
                                                   int* __restrict__ csr) {
    int id = blockIdx.x * 256 + threadIdx.x;
    if (id >= 3 * NE) return;
    int t = id / NE;
    int i = id - t * NE;
    int src = ei[(t * 2 + 0) * NE + i];
    int dst = ei[(t * 2 + 1) * NE + i];
    int p = atomicAdd(&deg[t * NN + dst], 1);
    if (p < DEG_CAP) csr[((long)t * NN + dst) * DEG_CAP + p] = src;
}

__global__ __launch_bounds__(256) void k_pack_deg(const int* __restrict__ deg,
                                                  int4* __restrict__ degp) {
    int n = blockIdx.x * 256 + threadIdx.x;
    if (n >= NNP) return;
    int4 v; v.x = 0; v.y = 0; v.z = 0; v.w = 0;
    if (n < NN) { v.x = deg[n]; v.y = deg[NN + n]; v.z = deg[2 * NN + n]; }
    degp[n] = v;
}

// ---------------------------------------------------------------------------
// Bf: FRAGMENT-ORDERED weights. n' = c*4 + sec (sec-minor). For MFMA
// 32x32x16 B-operand, lane = kg*32 + nl supplies B[n' = nb*32+nl]
// [k = k16*16 + kg*8 + e]. Fragment (nb,k16) = contiguous 1KB.
// K layout: k<384 -> A_cat (Wm @ Wih_sec^T), k>=384 -> h (Whh_sec).
// ---------------------------------------------------------------------------
__global__ __launch_bounds__(512) void k_build_w(const float* __restrict__ Wmsg,
                                                 const float* __restrict__ Wih,
                                                 const float* __restrict__ Whh,
                                                 unsigned short* __restrict__ Bf) {
    int np = blockIdx.x;       // 0..511 permuted col
    int k = threadIdx.x;       // 0..511
    int c = np >> 2, sec = np & 3;
    float v = 0.f;
    if (k < 384) {
        if (sec < 3) {
            int t = k >> 7, kk = k & 127;
            const float* wm = Wmsg + ((long)t * HID + kk) * HID;
            const float* wi = Wih + (long)(sec * HID + c) * HID;
            float s = 0.f;
            for (int j = 0; j < HID; j++) s += wm[j] * wi[j];
            v = s;
        }
    } else {
        int kk = k - 384;
        if (sec == 0)      v = Whh[(long)c * HID + kk];
        else if (sec == 1) v = Whh[(long)(HID + c) * HID + kk];
        else if (sec == 3) v = Whh[(long)(2 * HID + c) * HID + kk];
    }
    int nb = np >> 5, nl = np & 31;
    int k16 = k >> 4, kgg = (k >> 3) & 1, e = k & 7;
    Bf[((((nb * 32 + k16) * 2 + kgg) * 32 + nl) << 3) + e] = f2bf(v);
}

__global__ __launch_bounds__(512) void k_build_bias(const float* __restrict__ bih,
                                                    const float* __restrict__ bhh,
                                                    const float* __restrict__ bmsg,
                                                    const float* __restrict__ Wih,
                                                    float* __restrict__ bbig,
                                                    float* __restrict__ Bdeg) {
    int np = threadIdx.x;      // 0..511 permuted
    int c = np >> 2, sec = np & 3;
    float b;
    if (sec == 0)      b = bih[c] + bhh[c];
    else if (sec == 1) b = bih[HID + c] + bhh[HID + c];
    else if (sec == 2) b = bih[2 * HID + c];
    else               b = bhh[2 * HID + c];
    bbig[np] = b;
    for (int t = 0; t < 3; t++) {
        float s = 0.f;
        if (sec < 3) {
            const float* wi = Wih + (long)(sec * HID + c) * HID;
            const float* bm = bmsg + t * HID;
            for (int j = 0; j < HID; j++) s += bm[j] * wi[j];
        }
        Bdeg[t * 512 + np] = s;
    }
}

// ---------------------------------------------------------------------------
// FUSED step: gather (agg) -> LDS A-frags -> GEMM -> gates -> Yout.
// Phase 1: wave = 8 nodes; 16-lane group per edge-type (sec 0..2) + h (sec 3);
//   csr indices vector-loaded up front, __shfl-broadcast in loop; each node's
//   512-ch row lands in LDS fragment layout via ONE ds_write_b128 (64 lanes).
//   Eliminates the X intermediate (-200MB global traffic/step, -1 dispatch).
// Phase 2: GEMM (R12 structure, full-K, barrier-free): BM=64, BN=512, 8 waves
//   x (64x64 tile, acc[2][2]=64 AGPR); B from L2, fragment-ordered.
// Phase 3: epilogue v2 (R12 verbatim), reads h from Yin, writes ONLY Yout.
// Race-safety: Y ping-pong (Yin read-only, Yout write-only per step).
// ---------------------------------------------------------------------------
__global__ __launch_bounds__(512, 4) void k_step(
        const unsigned short* __restrict__ Yin,
        unsigned short* __restrict__ Yout,
        const unsigned short* __restrict__ Bf,
        const float* __restrict__ bbig, const float* __restrict__ Bdeg,
        const int4* __restrict__ degp,
        const int* __restrict__ deg,
        const int* __restrict__ csr) {
    __shared__ char lds[66048];     // A frags 64KB; EX [32][516] f32 overlays

    const int tid = threadIdx.x;
    const int lane = tid & 63;
    const int wv = tid >> 6;        // 0..7
    const int sec = lane >> 4;      // 0..2 = edge types, 3 = h
    const int c16 = lane & 15;
    const long row0 = (long)blockIdx.x * 64;

    // ---- phase 1: fused gather -> A-frags ----
#pragma unroll
    for (int i = 0; i < 8; i++) {
        const int rloc = wv * 8 + i;        // row in tile 0..63
        const long n = row0 + rloc;
        int d = 0, il0 = 0, il1 = 0;
        if (sec < 3 && n < NN) {
            d = deg[sec * NN + n];
            if (d > DEG_CAP) d = DEG_CAP;
            const long cb = ((long)sec * NN + n) * DEG_CAP;
            il0 = csr[cb + c16];
            il1 = csr[cb + 16 + c16];
        }
        float ac[8] = {0.f, 0.f, 0.f, 0.f, 0.f, 0.f, 0.f, 0.f};
#pragma unroll 2
        for (int j = 0; j < d; j++) {       // d uniform within 16-lane group
            int idx = __shfl((j < 16) ? il0 : il1, (lane & 48) + (j & 15));
            short8 v = *(const short8*)(Yin + (long)idx * HID + c16 * 8);
#pragma unroll
            for (int q = 0; q < 8; q++) ac[q] += bf2f((unsigned short)v[q]);
        }
        short8 o;
        if (sec == 3) {
            o = *(const short8*)(Yin + n * HID + c16 * 8);
        } else {
#pragma unroll
            for (int q = 0; q < 8; q++) o[q] = (short)f2bf(ac[q]);
        }
        // frag layout: k = sec*128 + c16*8 (+q); k16 = sec*8 + c16/2; kg = c16&1
        const int k16 = sec * 8 + (c16 >> 1);
        const int f = k16 * 2 + (rloc >> 5);
        *(short8*)(lds + f * 1024 + (((c16 & 1) << 5) + (rloc & 31)) * 16) = o;
    }

    // ---- phase 2: GEMM ----
    const int r31 = lane & 31;
    const unsigned short* pB0 = Bf + (wv * 2 + 0) * 16384 + lane * 8;
    const unsigned short* pB1 = Bf + (wv * 2 + 1) * 16384 + lane * 8;

    f32x16 acc[2][2];               // [mt (32-row half)][ct (32-col half)]
#pragma unroll
    for (int i = 0; i < 2; i++)
#pragma unroll
        for (int j = 0; j < 2; j++) acc[i][j] = (f32x16)(0.0f);

    __syncthreads();                // A-frags complete

#pragma unroll
    for (int k16 = 0; k16 < 32; k16++) {
        short8 a0 = *(const short8*)(lds + (k16 * 2 + 0) * 1024 + lane * 16);
        short8 a1 = *(const short8*)(lds + (k16 * 2 + 1) * 1024 + lane * 16);
        short8 b0 = *(const short8*)(pB0 + k16 * 512);
        short8 b1 = *(const short8*)(pB1 + k16 * 512);
        acc[0][0] = MFMA(a0, b0, acc[0][0]);
        acc[0][1] = MFMA(a0, b1, acc[0][1]);
        acc[1][0] = MFMA(a1, b0, acc[1][0]);
        acc[1][1] = MFMA(a1, b1, acc[1][1]);
    }

    // ---- phase 3: epilogue v2; EX = [32 rows][516] f32 ----
    float* EX = (float*)lds;
    const int ch = tid & 127;               // channel 0..127
    const int r5b = tid >> 7;               // 0..3
    const float4 bb = *(const float4*)(bbig + ch * 4);
    const float4 q0v = *(const float4*)(Bdeg + ch * 4);
    const float4 q1v = *(const float4*)(Bdeg + 512 + ch * 4);
    const float4 q2v = *(const float4*)(Bdeg + 1024 + ch * 4);
    const int kg = lane >> 5;

#pragma unroll
    for (int half = 0; half < 2; half++) {
        __syncthreads();
#pragma unroll
        for (int ct = 0; ct < 2; ct++) {
            const int col = wv * 64 + ct * 32 + r31;
#pragma unroll
            for (int reg = 0; reg < 16; reg++) {
                int r5 = (reg & 3) + 8 * (reg >> 2) + 4 * kg;
                EX[r5 * 516 + col] = half ? acc[1][ct][reg] : acc[0][ct][reg];
            }
        }
        __syncthreads();
#pragma unroll
        for (int i = 0; i < 8; i++) {
            const int r5 = r5b + 4 * i;     // 0..31
            long grow = row0 + half * 32 + r5;
            int4 dg = degp[grow];
            float dgx = (float)dg.x, dgy = (float)dg.y, dgz = (float)dg.z;
            float4 v = *(const float4*)(EX + r5 * 516 + ch * 4);
            float Sr = v.x + bb.x + dgx * q0v.x + dgy * q1v.x + dgz * q2v.x;
            float Sz = v.y + bb.y + dgx * q0v.y + dgy * q1v.y + dgz * q2v.y;
            float In = v.z + bb.z + dgx * q0v.z + dgy * q1v.z + dgz * q2v.z;
            float Hn = v.w + bb.w;          // sec3 deg-bias is 0 by construction
            float rr = sigm(Sr);
            float zz = sigm(Sz);
            float tt = In + rr * Hn;
            float ee = __expf(2.f * tt);
            float nn = 1.f - 2.f / (ee + 1.f);
            float hv = (1.f - zz) * nn + zz * bf2f(Yin[grow * HID + ch]);
            Yout[grow * HID + ch] = f2bf(hv);
        }
    }
}

// ---------------------------------------------------------------------------
// Readout: out[g] += sigmoid(h@Wg.T+bg) * (h@Wp.T+bp). h from Y bf16.
// ---------------------------------------------------------------------------
__global__ __launch_bounds__(256) void k_readout(const unsigned short* __restrict__ Y,
                                                 const int* __restrict__ n2g,
                                                 const float* __restrict__ Wp,
                                                 const float* __restrict__ bp,
                                                 const float* __restrict__ Wg,
                                                 const float* __restrict__ bg,
                                                 float* __restrict__ out) {
    __shared__ float hs[32][132];
    __shared__ float Ws[64][129];
    int tid = threadIdx.x;
    long row0 = (long)blockIdx.x * 32;
    int rg = tid >> 5, cg = tid & 31;
    float acc[4][4];
#pragma unroll
    for (int r = 0; r < 4; r++)
#pragma unroll
        for (int c = 0; c < 4; c++) acc[r][c] = 0.f;

#pragma unroll
    for (int p = 0; p < 2; p++) {
        int e = p * 256 + tid;
        int r = e >> 4, c8 = e & 15;
        short8 v = *(const short8*)(Y + (row0 + r) * HID + c8 * 8);
#pragma unroll
        for (int j = 0; j < 8; j++) hs[r][c8 * 8 + j] = bf2f((unsigned short)v[j]);
    }
    for (int kc = 0; kc < 128; kc += 64) {
        __syncthreads();
#pragma unroll
        for (int p = 0; p < 8; p++) {
            int idx = p * 256 + tid;
            int j = idx >> 4, q = idx & 15;
            const float* Wsrc = (j < 64) ? Wp : Wg;
            float4 w = *(const float4*)&Wsrc[(j & 63) * HID + kc + q * 4];
            Ws[q * 4 + 0][j] = w.x;
            Ws[q * 4 + 1][j] = w.y;
            Ws[q * 4 + 2][j] = w.z;
            Ws[q * 4 + 3][j] = w.w;
        }
        __syncthreads();
#pragma unroll 8
        for (int k = 0; k < 64; k++) {
            float a[4], w[4];
#pragma unroll
            for (int r = 0; r < 4; r++) a[r] = hs[rg * 4 + r][kc + k];
#pragma unroll
            for (int c = 0; c < 4; c++) w[c] = Ws[k][cg + 32 * c];
#pragma unroll
            for (int r = 0; r < 4; r++)
#pragma unroll
                for (int c = 0; c < 4; c++) acc[r][c] += a[r] * w[c];
        }
    }
#pragma unroll
    for (int r = 0; r < 4; r++) {
        long row = row0 + rg * 4 + r;
        if (row < NN) {
            int g = n2g[row];
            float pv0 = acc[r][0] + bp[cg];
            float pv1 = acc[r][1] + bp[cg + 32];
            float gv0 = acc[r][2] + bg[cg];
            float gv1 = acc[r][3] + bg[cg + 32];
            atomicAdd(&out[g * EMB + cg],      pv0 * sigm(gv0));
            atomicAdd(&out[g * EMB + cg + 32], pv1 * sigm(gv1));
        }
    }
}

// ---------------------------------------------------------------------------
extern "C" void kernel_launch(void* const* d_in, const int* in_sizes, int n_in,
                              void* d_out, int out_size, void* d_ws, size_t ws_size,
                              hipStream_t stream) {
    const float* node_features = (const float*)d_in[0];
    const int*   edge_index    = (const int*)d_in[1];
    const int*   n2g           = (const int*)d_in[2];
    const float* W_msg         = (const float*)d_in[3];
    const float* b_msg         = (const float*)d_in[4];
    const float* W_ih          = (const float*)d_in[5];
    const float* W_hh          = (const float*)d_in[6];
    const float* b_ih          = (const float*)d_in[7];
    const float* b_hh          = (const float*)d_in[8];
    const float* W_proj        = (const float*)d_in[9];
    const float* b_proj        = (const float*)d_in[10];
    const float* W_gate        = (const float*)d_in[11];
    const float* b_gate        = (const float*)d_in[12];

    char* ws = (char*)d_ws;
    unsigned short* Y0   = (unsigned short*)(ws);                 //  25,624,576 B
    unsigned short* Y1   = (unsigned short*)(ws + 25624576);      //  25,624,576 B
    unsigned short* Bf   = (unsigned short*)(ws + 51249152);      //     524,288 B
    float*          bbig = (float*)         (ws + 51773440);      //       2,048 B
    float*          Bdeg = (float*)         (ws + 51775488);      //       6,144 B
    int4*           degp = (int4*)          (ws + 51781632);      //   1,601,536 B
    int*            deg  = (int*)           (ws + 53383168);      //   1,200,000 B
    int*            csr  = (int*)           (ws + 54583168);      //  38,400,000 B -> 92,983,168

    float* out = (float*)d_out;

    hipMemsetAsync(out, 0, (size_t)NG * EMB * sizeof(float), stream);
    hipMemsetAsync(deg, 0, (size_t)3 * NN * sizeof(int), stream);

    k_init<<<dim3((NNP * HID) / 256), dim3(256), 0, stream>>>(node_features, Y0);
    k_build_csr<<<dim3((3 * NE + 255) / 256), dim3(256), 0, stream>>>(edge_index, deg, csr);
    k_pack_deg<<<dim3(NNP / 256), dim3(256), 0, stream>>>(deg, degp);
    k_build_w<<<dim3(512), dim3(512), 0, stream>>>(W_msg, W_ih, W_hh, Bf);
    k_build_bias<<<dim3(1), dim3(512), 0, stream>>>(b_ih, b_hh, b_msg, W_ih, bbig, Bdeg);

    // Y ping-pong: s0 Y0->Y1, s1 Y1->Y0, s2 Y0->Y1, s3 Y1->Y0; final h in Y0
    k_step<<<dim3(NNP / 64), dim3(512), 0, stream>>>(Y0, Y1, Bf, bbig, Bdeg, degp, deg, csr);
    k_step<<<dim3(NNP / 64), dim3(512), 0, stream>>>(Y1, Y0, Bf, bbig, Bdeg, degp, deg, csr);
    k_step<<<dim3(NNP / 64), dim3(512), 0, stream>>>(Y0, Y1, Bf, bbig, Bdeg, degp, deg, csr);
    k_step<<<dim3(NNP / 64), dim3(512), 0, stream>>>(Y1, Y0, Bf, bbig, Bdeg, degp, deg, csr);

    k_readout<<<dim3(NN / 32), dim3(256), 0, stream>>>(Y0, n2g, W_proj, b_proj,
                                                       W_gate, b_gate, out);
}